// Round 5
// baseline (2405.502 us; speedup 1.0000x reference)
//
#include <hip/hip_runtime.h>

// ---------------------------------------------------------------------------
// S2S RNN (encoder/decoder Elman + output log-softmax) on MI355X.
// fp32 in/out, bf16 operands + fp32 accumulate internally.
//
// Round-11: LDS-bandwidth attack on the compute phase.
// r10 post-mortem: every wave reads the FULL 32KB h-image per step as MFMA
// B-fragments; 8 waves/CU = 256KB/CU-step (~3000cyc) — the handshake win was
// eaten by ds_read. Also r10's contiguous-64B staging writes were 16-way
// bank-conflicted (counter 3.45e7 -> 5.55e7). This round:
//   - 2 j-tiles/wave (32 j), Whh in 256 VGPRs (w0/w1[32]): each h fragment
//     feeds TWO MFMAs -> ds_read:MFMA = 1:2; 8 WGs x 256 thr (4 waves,
//     1 wave/SIMD, __launch_bounds__(256,1)).
//   - staging map transposed: thread t stages (row t&15, 128B seg t>>4):
//     b128 writes at the 8-lane/position floor; poll region = ONE producer.
//   - s_setprio(1) around MFMA+produce, 0 during poll.
// Kept from r9/r10: IC-hot 8-slot window, per-thread data-poll (8x dwordx4
// sc0 sc1 + poison check), re-poison s-2, 0xAAAA->0xAAAB fixup, NT states
// stream, raw lgkm-only step barrier, proj-table xp. ws ~75 MB.
// ---------------------------------------------------------------------------

typedef short short8 __attribute__((ext_vector_type(8)));
typedef float floatx4 __attribute__((ext_vector_type(4)));
typedef unsigned int uint4v __attribute__((ext_vector_type(4)));

// ---- ws layout (~75 MB) ----
#define WS_WIN    0ull                        // 2 MB: [8][128][1024] bf16 window
#define WS_STATES (2ull << 20)                // 64 MB: [256][128][1024] bf16
#define WS_WB     (66ull << 20)               // weights/proj region

#define HS_STRIDE 1032  // shorts per LDS row (16B-aligned, +16B pad)

__device__ __forceinline__ float bf2f(unsigned short u) {
  union { unsigned u; float f; } x; x.u = ((unsigned)u) << 16; return x.f;
}
__device__ __forceinline__ unsigned short f2bf(float f) {
  union { float f; unsigned u; } x; x.f = f;
  unsigned r = x.u + 0x7FFFu + ((x.u >> 16) & 1u);  // RNE
  return (unsigned short)(r >> 16);
}
__device__ __forceinline__ unsigned pkminu16(unsigned a, unsigned b) {
  unsigned d;
  asm("v_pk_min_u16 %0, %1, %2" : "=v"(d) : "v"(a), "v"(b));
  return d;
}

// fp32 -> bf16 bulk convert, 4 elems/thread. n multiple of 1024.
__global__ __launch_bounds__(256) void cvt_kernel(
    const float* __restrict__ src, unsigned short* __restrict__ dst, int n)
{
  const int i = (blockIdx.x * 256 + threadIdx.x) * 4;
  if (i >= n) return;
  const float4 v = *(const float4*)(src + i);
  unsigned short o[4] = {f2bf(v.x), f2bf(v.y), f2bf(v.z), f2bf(v.w)};
  *(uint2*)(dst + i) = *(const uint2*)o;
}

// ---------------------------------------------------------------------------
// C[M,N] = gather(A)[M,K] . B[N,K]^T (+ fp32 bias), bf16 operands, fp32 acc.
// 64x64 WG tile, 4 waves, wave tile 16x64 via 16x16x32 bf16 MFMA.
// mode 0: dense rows.
// mode 3: A row m -> Abase + ((m&255)*128 + (m>>8)) * 1024  ([t][b][j] states)
// ---------------------------------------------------------------------------
__global__ __launch_bounds__(256) void gemm_bt_kernel(
    const unsigned short* __restrict__ Abase,
    const int mode,
    const unsigned short* __restrict__ Bmat,
    const float* __restrict__ bias0,
    const float* __restrict__ bias1,
    unsigned short* __restrict__ outp_bf,
    float* __restrict__ outp_f,
    const int K, const int N, const int nbn)
{
  __shared__ unsigned short As[64][264];
  __shared__ unsigned short Bs[64][264];
  __shared__ const unsigned short* rowsrc[64];

  const int tid = threadIdx.x;
  const int lane = tid & 63;
  const int wave = tid >> 6;
  const int bn = blockIdx.x % nbn;
  const int bm = blockIdx.x / nbn;
  const int m0 = bm * 64;
  const int j0 = bn * 64;

  if (tid < 64) {
    const int m = m0 + tid;
    const unsigned short* src;
    if (mode == 0) {
      src = Abase + (size_t)m * K;
    } else {  // mode 3
      src = Abase + ((size_t)(m & 255) * 128 + (m >> 8)) * 1024;
    }
    rowsrc[tid] = src;
  }

  const floatx4 zf = {0.f, 0.f, 0.f, 0.f};
  floatx4 acc0 = zf, acc1 = zf, acc2 = zf, acc3 = zf;

  for (int kc = 0; kc < K; kc += 256) {
    __syncthreads();
#pragma unroll
    for (int i = 0; i < 8; ++i) {
      const int idx = i * 256 + tid;
      const int r = idx >> 5;
      const int c = idx & 31;
      const unsigned short* s = rowsrc[r];
      *(short8*)&As[r][c * 8] = *(const short8*)(s + kc + c * 8);
      *(short8*)&Bs[r][c * 8] =
          *(const short8*)(Bmat + (size_t)(j0 + r) * K + kc + c * 8);
    }
    __syncthreads();
    const int ar = 16 * wave + (lane & 15);
    const int kq = (lane >> 4) * 8;
#pragma unroll
    for (int kk = 0; kk < 8; ++kk) {
      const short8 a = *(const short8*)&As[ar][kk * 32 + kq];
      const short8 bv0 = *(const short8*)&Bs[(lane & 15)][kk * 32 + kq];
      acc0 = __builtin_amdgcn_mfma_f32_16x16x32_bf16(a, bv0, acc0, 0, 0, 0);
      const short8 bv1 = *(const short8*)&Bs[16 + (lane & 15)][kk * 32 + kq];
      acc1 = __builtin_amdgcn_mfma_f32_16x16x32_bf16(a, bv1, acc1, 0, 0, 0);
      const short8 bv2 = *(const short8*)&Bs[32 + (lane & 15)][kk * 32 + kq];
      acc2 = __builtin_amdgcn_mfma_f32_16x16x32_bf16(a, bv2, acc2, 0, 0, 0);
      const short8 bv3 = *(const short8*)&Bs[48 + (lane & 15)][kk * 32 + kq];
      acc3 = __builtin_amdgcn_mfma_f32_16x16x32_bf16(a, bv3, acc3, 0, 0, 0);
    }
  }

  float bs[4] = {0.f, 0.f, 0.f, 0.f};
  if (bias0) {
#pragma unroll
    for (int nt = 0; nt < 4; ++nt) {
      const int jj = j0 + nt * 16 + (lane & 15);
      bs[nt] = bias0[jj] + bias1[jj];
    }
  }
  __syncthreads();
  const int rbase = 16 * wave + (lane >> 4) * 4;
  const int cl = lane & 15;

  if (outp_bf) {
#pragma unroll
    for (int i = 0; i < 4; ++i) {
      As[rbase + i][cl]      = f2bf(acc0[i] + bs[0]);
      As[rbase + i][16 + cl] = f2bf(acc1[i] + bs[1]);
      As[rbase + i][32 + cl] = f2bf(acc2[i] + bs[2]);
      As[rbase + i][48 + cl] = f2bf(acc3[i] + bs[3]);
    }
    __syncthreads();
#pragma unroll
    for (int i = 0; i < 2; ++i) {
      const int idx = i * 256 + tid;
      const int r = idx >> 3;
      const int c = idx & 7;
      *(short8*)(outp_bf + (size_t)(m0 + r) * N + j0 + c * 8) =
          *(const short8*)&As[r][c * 8];
    }
  } else {
    float (*Asf)[66] = (float(*)[66]) & As[0][0];
#pragma unroll
    for (int i = 0; i < 4; ++i) {
      Asf[rbase + i][cl]      = acc0[i] + bs[0];
      Asf[rbase + i][16 + cl] = acc1[i] + bs[1];
      Asf[rbase + i][32 + cl] = acc2[i] + bs[2];
      Asf[rbase + i][48 + cl] = acc3[i] + bs[3];
    }
    __syncthreads();
#pragma unroll
    for (int i = 0; i < 4; ++i) {
      const int idx = i * 256 + tid;
      const int r = idx >> 4;
      const int c = idx & 15;
      *(float4*)(outp_f + (size_t)(m0 + r) * N + j0 + c * 4) =
          *(const float4*)&Asf[r][c * 4];
    }
  }
}

// ---------------------------------------------------------------------------
// Round-11 recurrence. 64 WGs x 256 thr; group g = blockIdx&7 owns batch rows
// [16g,16g+16); 8 WGs/group cover 1024 cols (128/WG; 4 waves x 32 j each via
// 2 j-tiles/wave, Whh in 256 VGPRs).
// ---------------------------------------------------------------------------
__global__ __launch_bounds__(256, 1) void rnn_scan7_kernel(
    const unsigned short* __restrict__ WhhE,
    const unsigned short* __restrict__ WhhD,
    const unsigned short* __restrict__ projE,
    const unsigned short* __restrict__ projD,
    const float* __restrict__ decBih,
    const float* __restrict__ decBhh,
    const int* __restrict__ intoks,     // inputs  [128][256] int32
    const int* __restrict__ outtoks,    // outputs [128][256] int32
    unsigned short* __restrict__ win,   // [8][128][1024] window slots
    unsigned short* __restrict__ states)// [256][128][1024] decoder states
{
  __shared__ unsigned short hs[2 * 16 * HS_STRIDE];  // double-buffered
  __shared__ int toks[16 * 257];

  const int tid = threadIdx.x;
  const int lane = tid & 63;
  const int wave = tid >> 6;                   // 0..3
  const int g = blockIdx.x & 7;
  const int slot = blockIdx.x >> 3;            // 0..7
  const int b0 = g * 16;
  const int q = lane >> 4;
  const int cl = lane & 15;
  const int jwb = slot * 128 + wave * 32;      // wave's 32-column base
  const int jq0 = jwb + q * 4;                 // tile-0 quad
  const int jq1 = jwb + 16 + q * 4;            // tile-1 quad
  // Staging: thread t handles 128B chunk (row t&15, byte-cols (t>>4)*128..),
  // i.e. j-cols seg*64..seg*64+63, produced by WG seg>>1 of this group.
  const int prow = tid & 15;                   // 0..15
  const int pseg = tid >> 4;                   // 0..15
  const bool own = ((pseg >> 1) == slot);

  short8 w0[32], w1[32];  // Whh[jwb+cl][:], Whh[jwb+16+cl][:] — 256 VGPRs
  const floatx4 zf = {0.f, 0.f, 0.f, 0.f};
  unsigned long long obp0 = 0, obp1 = 0;  // own h(s-1): (b0+cl, jq0/jq1 ..+3)
  const size_t prodoff0 = (size_t)(b0 + cl) * 1024 + jq0;
  const size_t prodoff1 = (size_t)(b0 + cl) * 1024 + jq1;

  for (int phase = 0; phase < 2; ++phase) {
    const unsigned short* Whh = phase ? WhhD : WhhE;
    const unsigned short* proj = phase ? projD : projE;
    const int* gt = phase ? outtoks : intoks;
    {
      const unsigned short* wp0 = Whh + (size_t)(jwb + cl) * 1024 + q * 8;
      const unsigned short* wp1 = Whh + (size_t)(jwb + 16 + cl) * 1024 + q * 8;
#pragma unroll
      for (int kk = 0; kk < 32; ++kk) {
        w0[kk] = *(const short8*)(wp0 + kk * 32);
        w1[kk] = *(const short8*)(wp1 + kk * 32);
      }
    }
    float xb0[4], xb1[4];
    if (phase) {  // decoder t==0 input is zero -> xp = bih+bhh (fp32, exact)
#pragma unroll
      for (int i = 0; i < 4; ++i) {
        xb0[i] = decBih[jq0 + i] + decBhh[jq0 + i];
        xb1[i] = decBih[jq1 + i] + decBhh[jq1 + i];
      }
    }
    // stage this phase's token ids (16 rows x 256 steps) into LDS
    __syncthreads();
#pragma unroll
    for (int i = 0; i < 16; ++i) {
      const int idx = i * 256 + tid;
      toks[(idx >> 8) * 257 + (idx & 255)] =
          gt[(size_t)(b0 + (idx >> 8)) * 256 + (idx & 255)];
    }
    __syncthreads();

    for (int t = 0; t < 256; ++t) {
      const int s = phase * 256 + t;
      // xp gather (issued early; latency hides under the h poll)
      float xpf0[4], xpf1[4];
      {
        const int tt = phase ? (t > 0 ? t - 1 : 0) : t;
        const int tok = toks[cl * 257 + tt];
        const uint2 xr0 = *(const uint2*)(proj + (size_t)tok * 1024 + jq0);
        const uint2 xr1 = *(const uint2*)(proj + (size_t)tok * 1024 + jq1);
        const unsigned short* xs0 = (const unsigned short*)&xr0;
        const unsigned short* xs1 = (const unsigned short*)&xr1;
#pragma unroll
        for (int i = 0; i < 4; ++i) { xpf0[i] = bf2f(xs0[i]); xpf1[i] = bf2f(xs1[i]); }
        if (phase && t == 0) {
#pragma unroll
          for (int i = 0; i < 4; ++i) { xpf0[i] = xb0[i]; xpf1[i] = xb1[i]; }
        }
      }

      unsigned short* hsb = hs + (s & 1) * (16 * HS_STRIDE);
      if (s > 0) {
        // own slices straight from registers (no memory round-trip)
        *(unsigned long long*)&hsb[cl * HS_STRIDE + jq0] = obp0;
        *(unsigned long long*)&hsb[cl * HS_STRIDE + jq1] = obp1;
        if (!own) {
          const unsigned short* hprev =
              win + (size_t)((s - 1) & 7) * 131072 + b0 * 1024;
          const unsigned long long paddr =
              (unsigned long long)(hprev + prow * 1024 + pseg * 64);
          uint4v p0, p1, p2, p3, p4, p5, p6, p7;
          for (;;) {
            // 8x 16B coherent loads (L1/L2 bypass) of one 128B chunk from ONE
            // producer; all in flight together, one wait; re-issued per retry.
            asm volatile(
                "global_load_dwordx4 %0, %8, off sc0 sc1\n\t"
                "global_load_dwordx4 %1, %8, off offset:16 sc0 sc1\n\t"
                "global_load_dwordx4 %2, %8, off offset:32 sc0 sc1\n\t"
                "global_load_dwordx4 %3, %8, off offset:48 sc0 sc1\n\t"
                "global_load_dwordx4 %4, %8, off offset:64 sc0 sc1\n\t"
                "global_load_dwordx4 %5, %8, off offset:80 sc0 sc1\n\t"
                "global_load_dwordx4 %6, %8, off offset:96 sc0 sc1\n\t"
                "global_load_dwordx4 %7, %8, off offset:112 sc0 sc1\n\t"
                "s_waitcnt vmcnt(0)"
                : "=&v"(p0), "=&v"(p1), "=&v"(p2), "=&v"(p3),
                  "=&v"(p4), "=&v"(p5), "=&v"(p6), "=&v"(p7)
                : "v"(paddr)
                : "memory");
            // poison-validity: any short == 0xAAAA -> producer not done yet
            unsigned m0v = 0xFFFFFFFFu, m1v = 0xFFFFFFFFu;
            unsigned m2v = 0xFFFFFFFFu, m3v = 0xFFFFFFFFu;
#pragma unroll
            for (int i = 0; i < 4; ++i) {
              m0v = pkminu16(m0v, pkminu16(p0[i] ^ 0xAAAAAAAAu, p4[i] ^ 0xAAAAAAAAu));
              m1v = pkminu16(m1v, pkminu16(p1[i] ^ 0xAAAAAAAAu, p5[i] ^ 0xAAAAAAAAu));
              m2v = pkminu16(m2v, pkminu16(p2[i] ^ 0xAAAAAAAAu, p6[i] ^ 0xAAAAAAAAu));
              m3v = pkminu16(m3v, pkminu16(p3[i] ^ 0xAAAAAAAAu, p7[i] ^ 0xAAAAAAAAu));
            }
            const unsigned mm = pkminu16(pkminu16(m0v, m1v), pkminu16(m2v, m3v));
            const unsigned hz = (mm - 0x00010001u) & ~mm & 0x80008000u;
            if (hz == 0u) break;
            __builtin_amdgcn_s_sleep(1);
          }
          // stage the 128B chunk (b128 writes at the 8-lane/position floor)
          unsigned short* dst = &hsb[prow * HS_STRIDE + pseg * 64];
          *(uint4v*)(dst + 0)  = p0; *(uint4v*)(dst + 8)  = p1;
          *(uint4v*)(dst + 16) = p2; *(uint4v*)(dst + 24) = p3;
          *(uint4v*)(dst + 32) = p4; *(uint4v*)(dst + 40) = p5;
          *(uint4v*)(dst + 48) = p6; *(uint4v*)(dst + 56) = p7;
        }
      }
      // Raw barrier: drain LDS writes only; window/states/poison stores stay
      // in flight (never vmcnt-drained on the critical path).
      __builtin_amdgcn_sched_barrier(0);
      asm volatile("s_waitcnt lgkmcnt(0)" ::: "memory");
      __builtin_amdgcn_s_barrier();
      __builtin_amdgcn_sched_barrier(0);
      __builtin_amdgcn_s_setprio(1);

      floatx4 a00 = zf, a01 = zf, a10 = zf, a11 = zf;
      if (s > 0) {
        // each h fragment feeds BOTH j-tiles (ds_read:MFMA = 1:2)
        const unsigned short* hrow = &hsb[cl * HS_STRIDE + q * 8];
#pragma unroll
        for (int kk = 0; kk < 32; kk += 2) {
          const short8 h0 = *(const short8*)(hrow + (kk + 0) * 32);
          const short8 h1 = *(const short8*)(hrow + (kk + 1) * 32);
          a00 = __builtin_amdgcn_mfma_f32_16x16x32_bf16(w0[kk + 0], h0, a00, 0, 0, 0);
          a10 = __builtin_amdgcn_mfma_f32_16x16x32_bf16(w1[kk + 0], h0, a10, 0, 0, 0);
          a01 = __builtin_amdgcn_mfma_f32_16x16x32_bf16(w0[kk + 1], h1, a01, 0, 0, 0);
          a11 = __builtin_amdgcn_mfma_f32_16x16x32_bf16(w1[kk + 1], h1, a11, 0, 0, 0);
        }
      }
      unsigned short ob[8];
#pragma unroll
      for (int i = 0; i < 4; ++i) {
        const float pre0 = a00[i] + a01[i] + xpf0[i];
        const float pre1 = a10[i] + a11[i] + xpf1[i];
        const float e0 = __expf(2.f * pre0);
        const float e1 = __expf(2.f * pre1);
        ob[i]     = f2bf(1.f - 2.f / (e0 + 1.f));  // tanh
        ob[4 + i] = f2bf(1.f - 2.f / (e1 + 1.f));
        if (ob[i] == 0xAAAAu) ob[i] = 0xAAABu;         // anti-hang fixup
        if (ob[4 + i] == 0xAAAAu) ob[4 + i] = 0xAAABu;
      }
      obp0 = *(const unsigned long long*)&ob[0];
      obp1 = *(const unsigned long long*)&ob[4];
      // window stores first (critical handshake), IC-hot lines.
      unsigned long long* wbase =
          (unsigned long long*)(win + (size_t)(s & 7) * 131072);
      __hip_atomic_store((unsigned long long*)((unsigned short*)wbase + prodoff0),
                         obp0, __ATOMIC_RELAXED, __HIP_MEMORY_SCOPE_AGENT);
      __hip_atomic_store((unsigned long long*)((unsigned short*)wbase + prodoff1),
                         obp1, __ATOMIC_RELAXED, __HIP_MEMORY_SCOPE_AGENT);
      __builtin_amdgcn_s_setprio(0);
      // decoder states stream: nontemporal, background (never drained here).
      if (phase) {
        __builtin_nontemporal_store(
            obp0, (unsigned long long*)(states + (size_t)t * 131072 + prodoff0));
        __builtin_nontemporal_store(
            obp1, (unsigned long long*)(states + (size_t)t * 131072 + prodoff1));
      }
      // re-poison slot s-2 (post-barrier => all peers consumed it; retires
      // >=5 steps before reuse at s+6).
      if (s >= 2) {
        unsigned short* pb = win + (size_t)((s - 2) & 7) * 131072;
        __hip_atomic_store((unsigned long long*)(pb + prodoff0),
                           0xAAAAAAAAAAAAAAAAull, __ATOMIC_RELAXED,
                           __HIP_MEMORY_SCOPE_AGENT);
        __hip_atomic_store((unsigned long long*)(pb + prodoff1),
                           0xAAAAAAAAAAAAAAAAull, __ATOMIC_RELAXED,
                           __HIP_MEMORY_SCOPE_AGENT);
      }
    }
  }
}

// ---------------------------------------------------------------------------
// Rowwise log_softmax over V=512 with fp32 bias, fp32 in-place on d_out.
// ---------------------------------------------------------------------------
__global__ __launch_bounds__(256) void logsoftmax_kernel(
    float* __restrict__ logits, const float* __restrict__ outb)
{
  const int row = blockIdx.x * 4 + (threadIdx.x >> 6);
  const int lane = threadIdx.x & 63;
  float* rp = logits + (size_t)row * 512 + lane * 8;
  const float4 a0 = *(const float4*)rp;
  const float4 a1 = *(const float4*)(rp + 4);
  const float4 b0 = *(const float4*)(outb + lane * 8);
  const float4 b1 = *(const float4*)(outb + lane * 8 + 4);
  float v[8] = {a0.x + b0.x, a0.y + b0.y, a0.z + b0.z, a0.w + b0.w,
                a1.x + b1.x, a1.y + b1.y, a1.z + b1.z, a1.w + b1.w};
  float mx = v[0];
#pragma unroll
  for (int i = 1; i < 8; ++i) mx = fmaxf(mx, v[i]);
#pragma unroll
  for (int m = 1; m < 64; m <<= 1) mx = fmaxf(mx, __shfl_xor(mx, m, 64));
  float sum = 0.f;
#pragma unroll
  for (int i = 0; i < 8; ++i) sum += __expf(v[i] - mx);
#pragma unroll
  for (int m = 1; m < 64; m <<= 1) sum += __shfl_xor(sum, m, 64);
  const float lse = mx + __logf(sum);
  float4 o0 = {v[0] - lse, v[1] - lse, v[2] - lse, v[3] - lse};
  float4 o1 = {v[4] - lse, v[5] - lse, v[6] - lse, v[7] - lse};
  *(float4*)rp = o0;
  *(float4*)(rp + 4) = o1;
}

extern "C" void kernel_launch(void* const* d_in, const int* in_sizes, int n_in,
                              void* d_out, int out_size, void* d_ws, size_t ws_size,
                              hipStream_t stream)
{
  const int* inputs  = (const int*)d_in[0];
  const int* outputs = (const int*)d_in[1];
  const float* emb    = (const float*)d_in[2];
  const float* encWih = (const float*)d_in[3];
  const float* encWhh = (const float*)d_in[4];
  const float* encBih = (const float*)d_in[5];
  const float* encBhh = (const float*)d_in[6];
  const float* decWih = (const float*)d_in[7];
  const float* decWhh = (const float*)d_in[8];
  const float* decBih = (const float*)d_in[9];
  const float* decBhh = (const float*)d_in[10];
  const float* outW   = (const float*)d_in[11];
  const float* outB   = (const float*)d_in[12];

  char* ws = (char*)d_ws;
  unsigned short* win    = (unsigned short*)(ws + WS_WIN);
  unsigned short* states = (unsigned short*)(ws + WS_STATES);
  char* wb = ws + WS_WB;
  unsigned short* embB  = (unsigned short*)(wb + 0);
  unsigned short* eWihB = (unsigned short*)(wb + (512ull << 10));
  unsigned short* dWihB = (unsigned short*)(wb + (1ull << 20));
  unsigned short* eWhhB = (unsigned short*)(wb + (2ull << 20));
  unsigned short* dWhhB = (unsigned short*)(wb + (4ull << 20));
  unsigned short* outWB = (unsigned short*)(wb + (6ull << 20));
  unsigned short* projE = (unsigned short*)(wb + (7ull << 20));
  unsigned short* projD = (unsigned short*)(wb + (8ull << 20));
  float* logits = (float*)d_out;

  cvt_kernel<<<128, 256, 0, stream>>>(emb, embB, 512 * 256);
  cvt_kernel<<<256, 256, 0, stream>>>(encWih, eWihB, 1024 * 256);
  cvt_kernel<<<256, 256, 0, stream>>>(decWih, dWihB, 1024 * 256);
  cvt_kernel<<<1024, 256, 0, stream>>>(encWhh, eWhhB, 1024 * 1024);
  cvt_kernel<<<1024, 256, 0, stream>>>(decWhh, dWhhB, 1024 * 1024);
  cvt_kernel<<<512, 256, 0, stream>>>(outW, outWB, 512 * 1024);

  // projected-vocab tables: proj[v] = emb[v] @ Wih^T + bih + bhh  (512x1024)
  gemm_bt_kernel<<<128, 256, 0, stream>>>(embB, 0, eWihB, encBih, encBhh,
                                          projE, nullptr, 256, 1024, 16);
  gemm_bt_kernel<<<128, 256, 0, stream>>>(embB, 0, dWihB, decBih, decBhh,
                                          projD, nullptr, 256, 1024, 16);

  rnn_scan7_kernel<<<64, 256, 0, stream>>>(eWhhB, dWhhB, projE, projD,
                                           decBih, decBhh, inputs, outputs,
                                           win, states);

  gemm_bt_kernel<<<4096, 256, 0, stream>>>(states, 3, outWB, nullptr, nullptr,
                                           nullptr, logits, 1024, 512, 8);
  logsoftmax_kernel<<<8192, 256, 0, stream>>>(logits, outB);
}

// Round 6
// 1624.062 us; speedup vs baseline: 1.4812x; 1.4812x over previous
//
#include <hip/hip_runtime.h>

// ---------------------------------------------------------------------------
// S2S RNN (encoder/decoder Elman + output log-softmax) on MI355X.
// fp32 in/out, bf16 operands + fp32 accumulate internally.
//
// Round-12: return to the PROVEN round-5 recurrence structure (2.59 us/step,
// the only scheme that ever measured fastest) and shave its latency stages:
//   - flags padded to 64B stride (r5 had 16 flags in ONE line: every publish
//     bounced the line all pollers hammer).
//   - per-WAVE flags (64/group): publisher = own-wave vmcnt(0) drain + lane0
//     store (no WG syncthreads on the publish path); consumer = EVERY wave
//     polls all 64 flags (lane l <-> flag l, one ballot). Two syncthreads
//     and the wave0->WG broadcast leave the critical path.
//   - load stage: 8x 16B sc0sc1 asm loads + one vmcnt(0) (guaranteed valid
//     after poll; 16B coherent reads of peer atomic stores proven in r10/11).
//   - NT states store AFTER flag publish (HBM ack off the publish path);
//     raw lgkm-only step barrier (r9-proven); setprio(1) around MFMA.
// Kept from r7-r11 side-wins: proj-table xp (no 128MB xp tensors, no 2 big
// GEMMs), NT states stream, mode-3 final GEMM. Flag-validity argument is
// r5's: flag>=s  =>  h_s stored AND h_{s-1} consumed (loads precede MFMA
// precede store precede vmcnt(0) precede flag). ws ~75 MB.
// ---------------------------------------------------------------------------

typedef short short8 __attribute__((ext_vector_type(8)));
typedef float floatx4 __attribute__((ext_vector_type(4)));
typedef unsigned int uint4v __attribute__((ext_vector_type(4)));

// ---- ws layout (~75 MB) ----
#define WS_HBUF   0ull                        // 512 KB: [2][128][1024] bf16 ping-pong
#define WS_STATES (2ull << 20)                // 64 MB: [256][128][1024] bf16
#define WS_WB     (66ull << 20)               // weights/proj/flags region

#define HS_STRIDE 1032  // shorts per LDS row (16B-aligned, +16B pad)

__device__ __forceinline__ float bf2f(unsigned short u) {
  union { unsigned u; float f; } x; x.u = ((unsigned)u) << 16; return x.f;
}
__device__ __forceinline__ unsigned short f2bf(float f) {
  union { float f; unsigned u; } x; x.f = f;
  unsigned r = x.u + 0x7FFFu + ((x.u >> 16) & 1u);  // RNE
  return (unsigned short)(r >> 16);
}

// fp32 -> bf16 bulk convert, 4 elems/thread. n multiple of 1024.
__global__ __launch_bounds__(256) void cvt_kernel(
    const float* __restrict__ src, unsigned short* __restrict__ dst, int n)
{
  const int i = (blockIdx.x * 256 + threadIdx.x) * 4;
  if (i >= n) return;
  const float4 v = *(const float4*)(src + i);
  unsigned short o[4] = {f2bf(v.x), f2bf(v.y), f2bf(v.z), f2bf(v.w)};
  *(uint2*)(dst + i) = *(const uint2*)o;
}

// ---------------------------------------------------------------------------
// C[M,N] = gather(A)[M,K] . B[N,K]^T (+ fp32 bias), bf16 operands, fp32 acc.
// 64x64 WG tile, 4 waves, wave tile 16x64 via 16x16x32 bf16 MFMA.
// mode 0: dense rows.
// mode 3: A row m -> Abase + ((m&255)*128 + (m>>8)) * 1024  ([t][b][j] states)
// ---------------------------------------------------------------------------
__global__ __launch_bounds__(256) void gemm_bt_kernel(
    const unsigned short* __restrict__ Abase,
    const int mode,
    const unsigned short* __restrict__ Bmat,
    const float* __restrict__ bias0,
    const float* __restrict__ bias1,
    unsigned short* __restrict__ outp_bf,
    float* __restrict__ outp_f,
    const int K, const int N, const int nbn)
{
  __shared__ unsigned short As[64][264];
  __shared__ unsigned short Bs[64][264];
  __shared__ const unsigned short* rowsrc[64];

  const int tid = threadIdx.x;
  const int lane = tid & 63;
  const int wave = tid >> 6;
  const int bn = blockIdx.x % nbn;
  const int bm = blockIdx.x / nbn;
  const int m0 = bm * 64;
  const int j0 = bn * 64;

  if (tid < 64) {
    const int m = m0 + tid;
    const unsigned short* src;
    if (mode == 0) {
      src = Abase + (size_t)m * K;
    } else {  // mode 3
      src = Abase + ((size_t)(m & 255) * 128 + (m >> 8)) * 1024;
    }
    rowsrc[tid] = src;
  }

  const floatx4 zf = {0.f, 0.f, 0.f, 0.f};
  floatx4 acc0 = zf, acc1 = zf, acc2 = zf, acc3 = zf;

  for (int kc = 0; kc < K; kc += 256) {
    __syncthreads();
#pragma unroll
    for (int i = 0; i < 8; ++i) {
      const int idx = i * 256 + tid;
      const int r = idx >> 5;
      const int c = idx & 31;
      const unsigned short* s = rowsrc[r];
      *(short8*)&As[r][c * 8] = *(const short8*)(s + kc + c * 8);
      *(short8*)&Bs[r][c * 8] =
          *(const short8*)(Bmat + (size_t)(j0 + r) * K + kc + c * 8);
    }
    __syncthreads();
    const int ar = 16 * wave + (lane & 15);
    const int kq = (lane >> 4) * 8;
#pragma unroll
    for (int kk = 0; kk < 8; ++kk) {
      const short8 a = *(const short8*)&As[ar][kk * 32 + kq];
      const short8 bv0 = *(const short8*)&Bs[(lane & 15)][kk * 32 + kq];
      acc0 = __builtin_amdgcn_mfma_f32_16x16x32_bf16(a, bv0, acc0, 0, 0, 0);
      const short8 bv1 = *(const short8*)&Bs[16 + (lane & 15)][kk * 32 + kq];
      acc1 = __builtin_amdgcn_mfma_f32_16x16x32_bf16(a, bv1, acc1, 0, 0, 0);
      const short8 bv2 = *(const short8*)&Bs[32 + (lane & 15)][kk * 32 + kq];
      acc2 = __builtin_amdgcn_mfma_f32_16x16x32_bf16(a, bv2, acc2, 0, 0, 0);
      const short8 bv3 = *(const short8*)&Bs[48 + (lane & 15)][kk * 32 + kq];
      acc3 = __builtin_amdgcn_mfma_f32_16x16x32_bf16(a, bv3, acc3, 0, 0, 0);
    }
  }

  float bs[4] = {0.f, 0.f, 0.f, 0.f};
  if (bias0) {
#pragma unroll
    for (int nt = 0; nt < 4; ++nt) {
      const int jj = j0 + nt * 16 + (lane & 15);
      bs[nt] = bias0[jj] + bias1[jj];
    }
  }
  __syncthreads();
  const int rbase = 16 * wave + (lane >> 4) * 4;
  const int cl = lane & 15;

  if (outp_bf) {
#pragma unroll
    for (int i = 0; i < 4; ++i) {
      As[rbase + i][cl]      = f2bf(acc0[i] + bs[0]);
      As[rbase + i][16 + cl] = f2bf(acc1[i] + bs[1]);
      As[rbase + i][32 + cl] = f2bf(acc2[i] + bs[2]);
      As[rbase + i][48 + cl] = f2bf(acc3[i] + bs[3]);
    }
    __syncthreads();
#pragma unroll
    for (int i = 0; i < 2; ++i) {
      const int idx = i * 256 + tid;
      const int r = idx >> 3;
      const int c = idx & 7;
      *(short8*)(outp_bf + (size_t)(m0 + r) * N + j0 + c * 8) =
          *(const short8*)&As[r][c * 8];
    }
  } else {
    float (*Asf)[66] = (float(*)[66]) & As[0][0];
#pragma unroll
    for (int i = 0; i < 4; ++i) {
      Asf[rbase + i][cl]      = acc0[i] + bs[0];
      Asf[rbase + i][16 + cl] = acc1[i] + bs[1];
      Asf[rbase + i][32 + cl] = acc2[i] + bs[2];
      Asf[rbase + i][48 + cl] = acc3[i] + bs[3];
    }
    __syncthreads();
#pragma unroll
    for (int i = 0; i < 4; ++i) {
      const int idx = i * 256 + tid;
      const int r = idx >> 4;
      const int c = idx & 15;
      *(float4*)(outp_f + (size_t)(m0 + r) * N + j0 + c * 4) =
          *(const float4*)&Asf[r][c * 4];
    }
  }
}

// ---------------------------------------------------------------------------
// Round-12 recurrence. 128 WGs x 256 thr; group g = blockIdx&7 owns batch rows
// [16g,16g+16); 16 WGs/group cover 1024 cols (64/WG, 16/wave).
// Ping-pong hbuf + padded per-wave flags; all-wave poll; 16B coherent loads.
// ---------------------------------------------------------------------------
__global__ __launch_bounds__(256) void rnn_scan8_kernel(
    const unsigned short* __restrict__ WhhE,
    const unsigned short* __restrict__ WhhD,
    const unsigned short* __restrict__ projE,
    const unsigned short* __restrict__ projD,
    const float* __restrict__ decBih,
    const float* __restrict__ decBhh,
    const int* __restrict__ intoks,     // inputs  [128][256] int32
    const int* __restrict__ outtoks,    // outputs [128][256] int32
    unsigned short* __restrict__ hbuf,  // [2][128][1024] ping-pong h
    unsigned short* __restrict__ states,// [256][128][1024] decoder states
    unsigned int* __restrict__ flags)   // [8][64*16] per-wave flags, 64B pad
{
  __shared__ unsigned short hs[2 * 16 * HS_STRIDE];  // double-buffered
  __shared__ int toks[16 * 257];

  const int tid = threadIdx.x;
  const int lane = tid & 63;
  const int wave = tid >> 6;                   // 0..3
  const int g = blockIdx.x & 7;
  const int slot = blockIdx.x >> 3;            // 0..15
  const int b0 = g * 16;
  const int q = lane >> 4;
  const int cl = lane & 15;
  const int jwb = slot * 64 + wave * 16;       // wave's 16-column base
  const int jq4 = jwb + q * 4;                 // this thread's 4 output columns
  unsigned int* grpflags = flags + (size_t)g * 1024;  // 64 flags x 16-u32 pad
  const int myflag = (slot * 4 + wave) * 16;

  short8 w[32];  // Whh[jwb+cl][0:1024] A-fragments — 128 VGPRs
  const floatx4 zf = {0.f, 0.f, 0.f, 0.f};
  const size_t prodoff = (size_t)(b0 + cl) * 1024 + jq4;

  for (int phase = 0; phase < 2; ++phase) {
    const unsigned short* Whh = phase ? WhhD : WhhE;
    const unsigned short* proj = phase ? projD : projE;
    const int* gt = phase ? outtoks : intoks;
    {
      const unsigned short* wp = Whh + (size_t)(jwb + cl) * 1024 + q * 8;
#pragma unroll
      for (int kk = 0; kk < 32; ++kk) w[kk] = *(const short8*)(wp + kk * 32);
    }
    float xb[4] = {0.f, 0.f, 0.f, 0.f};
    if (phase) {  // decoder t==0 input is zero -> xp = bih+bhh (fp32, exact)
#pragma unroll
      for (int i = 0; i < 4; ++i) xb[i] = decBih[jq4 + i] + decBhh[jq4 + i];
    }
    // stage this phase's token ids (16 rows x 256 steps) into LDS
    __syncthreads();
#pragma unroll
    for (int i = 0; i < 16; ++i) {
      const int idx = i * 256 + tid;
      toks[(idx >> 8) * 257 + (idx & 255)] =
          gt[(size_t)(b0 + (idx >> 8)) * 256 + (idx & 255)];
    }
    __syncthreads();

    for (int t = 0; t < 256; ++t) {
      const int s = phase * 256 + t;
      // xp gather (issued early; latency hides under the flag poll)
      float xpf[4];
      {
        const int tt = phase ? (t > 0 ? t - 1 : 0) : t;
        const int tok = toks[cl * 257 + tt];
        const uint2 xr = *(const uint2*)(proj + (size_t)tok * 1024 + jq4);
        const unsigned short* xs = (const unsigned short*)&xr;
#pragma unroll
        for (int i = 0; i < 4; ++i) xpf[i] = bf2f(xs[i]);
        if (phase && t == 0) {
#pragma unroll
          for (int i = 0; i < 4; ++i) xpf[i] = xb[i];
        }
      }

      unsigned short* hsb = hs + (s & 1) * (16 * HS_STRIDE);
      if (s > 0) {
        // EVERY wave polls all 64 per-wave flags: lane l <-> flag l.
        // flag >= s  =>  peers stored h_s AND consumed h_{s-1}.
        const unsigned target = (unsigned)s;
        for (;;) {
          const unsigned f = __hip_atomic_load(&grpflags[lane * 16],
                                               __ATOMIC_RELAXED,
                                               __HIP_MEMORY_SCOPE_AGENT);
          if (__ballot(f < target) == 0ull) break;
          __builtin_amdgcn_s_sleep(1);
        }
        // guaranteed-valid image load: 8x 16B coherent loads, one wait.
        const unsigned short* hrb = hbuf + (size_t)(s & 1) * 131072 + b0 * 1024;
        uint4v p0, p1, p2, p3, p4, p5, p6, p7;
        {
          const unsigned long long a0 = (unsigned long long)(hrb + tid * 8);
          asm volatile(
              "global_load_dwordx4 %0, %8, off sc0 sc1\n\t"
              "global_load_dwordx4 %1, %9, off sc0 sc1\n\t"
              "global_load_dwordx4 %2, %10, off sc0 sc1\n\t"
              "global_load_dwordx4 %3, %11, off sc0 sc1\n\t"
              "global_load_dwordx4 %4, %12, off sc0 sc1\n\t"
              "global_load_dwordx4 %5, %13, off sc0 sc1\n\t"
              "global_load_dwordx4 %6, %14, off sc0 sc1\n\t"
              "global_load_dwordx4 %7, %15, off sc0 sc1\n\t"
              "s_waitcnt vmcnt(0)"
              : "=&v"(p0), "=&v"(p1), "=&v"(p2), "=&v"(p3),
                "=&v"(p4), "=&v"(p5), "=&v"(p6), "=&v"(p7)
              : "v"(a0),            "v"(a0 + 1 * 4096),
                "v"(a0 + 2 * 4096), "v"(a0 + 3 * 4096),
                "v"(a0 + 4 * 4096), "v"(a0 + 5 * 4096),
                "v"(a0 + 6 * 4096), "v"(a0 + 7 * 4096)
              : "memory");
        }
        __builtin_amdgcn_sched_barrier(0);
        // stage to LDS (r5 map: chunk gg = c*256+tid -> row gg>>7, col gg&127)
        {
          uint4v pp[8] = {p0, p1, p2, p3, p4, p5, p6, p7};
#pragma unroll
          for (int c = 0; c < 8; ++c) {
            const int gg = c * 256 + tid;
            *(uint4v*)&hsb[(gg >> 7) * HS_STRIDE + (gg & 127) * 8] = pp[c];
          }
        }
      }
      // Raw barrier: drain LDS writes only; stores stay in flight.
      __builtin_amdgcn_sched_barrier(0);
      asm volatile("s_waitcnt lgkmcnt(0)" ::: "memory");
      __builtin_amdgcn_s_barrier();
      __builtin_amdgcn_sched_barrier(0);
      __builtin_amdgcn_s_setprio(1);

      floatx4 acc0 = zf, acc1 = zf, acc2 = zf, acc3 = zf;
      if (s > 0) {
        // swapped operands: thread owns (row b0+cl, cols jq4..+3)
        const unsigned short* hrow = &hsb[cl * HS_STRIDE + q * 8];
#pragma unroll
        for (int kk = 0; kk < 32; kk += 4) {
          const short8 a0 = *(const short8*)(hrow + (kk + 0) * 32);
          const short8 a1 = *(const short8*)(hrow + (kk + 1) * 32);
          const short8 a2 = *(const short8*)(hrow + (kk + 2) * 32);
          const short8 a3 = *(const short8*)(hrow + (kk + 3) * 32);
          acc0 = __builtin_amdgcn_mfma_f32_16x16x32_bf16(w[kk + 0], a0, acc0, 0, 0, 0);
          acc1 = __builtin_amdgcn_mfma_f32_16x16x32_bf16(w[kk + 1], a1, acc1, 0, 0, 0);
          acc2 = __builtin_amdgcn_mfma_f32_16x16x32_bf16(w[kk + 2], a2, acc2, 0, 0, 0);
          acc3 = __builtin_amdgcn_mfma_f32_16x16x32_bf16(w[kk + 3], a3, acc3, 0, 0, 0);
        }
      }
      unsigned short ob[4];
#pragma unroll
      for (int i = 0; i < 4; ++i) {
        const float pre = acc0[i] + acc1[i] + acc2[i] + acc3[i] + xpf[i];
        const float e = __expf(2.f * pre);
        ob[i] = f2bf(1.f - 2.f / (e + 1.f));  // tanh
      }
      const unsigned long long obp = *(const unsigned long long*)ob;
      // h store (critical handshake) -> own-wave drain -> per-wave flag.
      __hip_atomic_store(
          (unsigned long long*)(hbuf + (size_t)((s + 1) & 1) * 131072 + prodoff),
          obp, __ATOMIC_RELAXED, __HIP_MEMORY_SCOPE_AGENT);
      asm volatile("s_waitcnt vmcnt(0)" ::: "memory");
      if (lane == 0)
        __hip_atomic_store(&grpflags[myflag], (unsigned)(s + 1),
                           __ATOMIC_RELAXED, __HIP_MEMORY_SCOPE_AGENT);
      __builtin_amdgcn_s_setprio(0);
      // decoder states stream: nontemporal, AFTER publish (ack off the path).
      if (phase) {
        __builtin_nontemporal_store(
            obp, (unsigned long long*)(states + (size_t)t * 131072 + prodoff));
      }
    }
  }
}

// ---------------------------------------------------------------------------
// Rowwise log_softmax over V=512 with fp32 bias, fp32 in-place on d_out.
// ---------------------------------------------------------------------------
__global__ __launch_bounds__(256) void logsoftmax_kernel(
    float* __restrict__ logits, const float* __restrict__ outb)
{
  const int row = blockIdx.x * 4 + (threadIdx.x >> 6);
  const int lane = threadIdx.x & 63;
  float* rp = logits + (size_t)row * 512 + lane * 8;
  const float4 a0 = *(const float4*)rp;
  const float4 a1 = *(const float4*)(rp + 4);
  const float4 b0 = *(const float4*)(outb + lane * 8);
  const float4 b1 = *(const float4*)(outb + lane * 8 + 4);
  float v[8] = {a0.x + b0.x, a0.y + b0.y, a0.z + b0.z, a0.w + b0.w,
                a1.x + b1.x, a1.y + b1.y, a1.z + b1.z, a1.w + b1.w};
  float mx = v[0];
#pragma unroll
  for (int i = 1; i < 8; ++i) mx = fmaxf(mx, v[i]);
#pragma unroll
  for (int m = 1; m < 64; m <<= 1) mx = fmaxf(mx, __shfl_xor(mx, m, 64));
  float sum = 0.f;
#pragma unroll
  for (int i = 0; i < 8; ++i) sum += __expf(v[i] - mx);
#pragma unroll
  for (int m = 1; m < 64; m <<= 1) sum += __shfl_xor(sum, m, 64);
  const float lse = mx + __logf(sum);
  float4 o0 = {v[0] - lse, v[1] - lse, v[2] - lse, v[3] - lse};
  float4 o1 = {v[4] - lse, v[5] - lse, v[6] - lse, v[7] - lse};
  *(float4*)rp = o0;
  *(float4*)(rp + 4) = o1;
}

extern "C" void kernel_launch(void* const* d_in, const int* in_sizes, int n_in,
                              void* d_out, int out_size, void* d_ws, size_t ws_size,
                              hipStream_t stream)
{
  const int* inputs  = (const int*)d_in[0];
  const int* outputs = (const int*)d_in[1];
  const float* emb    = (const float*)d_in[2];
  const float* encWih = (const float*)d_in[3];
  const float* encWhh = (const float*)d_in[4];
  const float* encBih = (const float*)d_in[5];
  const float* encBhh = (const float*)d_in[6];
  const float* decWih = (const float*)d_in[7];
  const float* decWhh = (const float*)d_in[8];
  const float* decBih = (const float*)d_in[9];
  const float* decBhh = (const float*)d_in[10];
  const float* outW   = (const float*)d_in[11];
  const float* outB   = (const float*)d_in[12];

  char* ws = (char*)d_ws;
  unsigned short* hbuf   = (unsigned short*)(ws + WS_HBUF);
  unsigned short* states = (unsigned short*)(ws + WS_STATES);
  char* wb = ws + WS_WB;
  unsigned short* embB  = (unsigned short*)(wb + 0);
  unsigned short* eWihB = (unsigned short*)(wb + (512ull << 10));
  unsigned short* dWihB = (unsigned short*)(wb + (1ull << 20));
  unsigned short* eWhhB = (unsigned short*)(wb + (2ull << 20));
  unsigned short* dWhhB = (unsigned short*)(wb + (4ull << 20));
  unsigned short* outWB = (unsigned short*)(wb + (6ull << 20));
  unsigned short* projE = (unsigned short*)(wb + (7ull << 20));
  unsigned short* projD = (unsigned short*)(wb + (8ull << 20));
  unsigned int*   flags = (unsigned int*)  (wb + (9ull << 20));
  float* logits = (float*)d_out;

  hipMemsetAsync(flags, 0, 8 * 1024 * sizeof(unsigned int), stream);

  cvt_kernel<<<128, 256, 0, stream>>>(emb, embB, 512 * 256);
  cvt_kernel<<<256, 256, 0, stream>>>(encWih, eWihB, 1024 * 256);
  cvt_kernel<<<256, 256, 0, stream>>>(decWih, dWihB, 1024 * 256);
  cvt_kernel<<<1024, 256, 0, stream>>>(encWhh, eWhhB, 1024 * 1024);
  cvt_kernel<<<1024, 256, 0, stream>>>(decWhh, dWhhB, 1024 * 1024);
  cvt_kernel<<<512, 256, 0, stream>>>(outW, outWB, 512 * 1024);

  // projected-vocab tables: proj[v] = emb[v] @ Wih^T + bih + bhh  (512x1024)
  gemm_bt_kernel<<<128, 256, 0, stream>>>(embB, 0, eWihB, encBih, encBhh,
                                          projE, nullptr, 256, 1024, 16);
  gemm_bt_kernel<<<128, 256, 0, stream>>>(embB, 0, dWihB, decBih, decBhh,
                                          projD, nullptr, 256, 1024, 16);

  rnn_scan8_kernel<<<128, 256, 0, stream>>>(eWhhB, dWhhB, projE, projD,
                                            decBih, decBhh, inputs, outputs,
                                            hbuf, states, flags);

  gemm_bt_kernel<<<4096, 256, 0, stream>>>(states, 3, outWB, nullptr, nullptr,
                                           nullptr, logits, 1024, 512, 8);
  logsoftmax_kernel<<<8192, 256, 0, stream>>>(logits, outB);
}